// Round 2
// baseline (372.465 us; speedup 1.0000x reference)
//
#include <hip/hip_runtime.h>

// Problem constants (from reference)
#define BB   32
#define CC   64
#define HH   224
#define WW   224
#define H2   226
#define W2   226
#define HID  8

constexpr unsigned NPLANE = BB * CC;      // 2048 (b,c) planes
constexpr unsigned XHW    = HH * WW;      // 50176 floats per x plane
constexpr unsigned HW2    = H2 * W2;      // 51076 floats per out plane
constexpr unsigned F4PP   = HH * (WW/4);  // 12544 float4 copies per plane

// Per-branch LDS weight layout: [w1 48][b1 8][w2 64][b2 8][w3 8][b3 1] = 137
__device__ __forceinline__ float mlp_eval(const float s[2][3],
                                          const float* __restrict__ W) {
    const float* W1 = W;        // 48
    const float* B1 = W + 48;   // 8
    const float* W2m = W + 56;  // 64
    const float* B2 = W + 120;  // 8
    const float* W3 = W + 128;  // 8
    const float  b3 = W[136];
    float y1[HID];
#pragma unroll
    for (int h = 0; h < HID; ++h) {
        float a = B1[h];
#pragma unroll
        for (int r = 0; r < 2; ++r)
#pragma unroll
            for (int k = 0; k < 3; ++k)
                a = fmaf(s[r][k], W1[h * 6 + r * 3 + k], a);
        y1[h] = fmaxf(a, 0.f);
    }
    float y2[HID];
#pragma unroll
    for (int o = 0; o < HID; ++o) {
        float a = B2[o];
#pragma unroll
        for (int h = 0; h < HID; ++h) a = fmaf(y1[h], W2m[o * 8 + h], a);
        y2[o] = fmaxf(a, 0.f);
    }
    float a = b3;
#pragma unroll
    for (int h = 0; h < HID; ++h) a = fmaf(y2[h], W3[h], a);
    return fmaxf(a, 0.f);
}

#define LOADW(br, pw1, pb1, pw2, pb2, pw3, pb3)                         \
    if (t < 48) wts[br][t] = pw1[t];                                    \
    if (t < 64) wts[br][56 + t] = pw2[t];                               \
    if (t < 8) {                                                        \
        wts[br][48 + t]  = pb1[t];                                      \
        wts[br][120 + t] = pb2[t];                                      \
        wts[br][128 + t] = pw3[t];                                      \
    }                                                                   \
    if (t == 0) wts[br][136] = pb3[0];

// ---------------------------------------------------------------------------
// One block per (b,c) plane. Fused: pad-copy + 4 border MLPs.
// ---------------------------------------------------------------------------
__global__ __launch_bounds__(256) void fused_pad_k(
    const float* __restrict__ x, float* __restrict__ out,
    const float* tw1, const float* tb1, const float* tw2, const float* tb2,
    const float* tw3, const float* tb3,
    const float* bw1, const float* bb1, const float* bw2, const float* bb2,
    const float* bw3, const float* bb3,
    const float* lw1, const float* lb1, const float* lw2, const float* lb2,
    const float* lw3, const float* lb3,
    const float* rw1, const float* rb1, const float* rw2, const float* rb2,
    const float* rw3, const float* rb3) {
    const unsigned bc = blockIdx.x;
    const unsigned t  = threadIdx.x;

    __shared__ float wts[4][137];       // 0=top 1=bottom 2=left 3=right
    __shared__ float Lcol[H2][2];       // padded cols 1,2   (rows 0..225)
    __shared__ float Rcol[H2][2];       // padded cols 223,224

    LOADW(0, tw1, tb1, tw2, tb2, tw3, tb3)
    LOADW(1, bw1, bb1, bw2, bb2, bw3, bb3)
    LOADW(2, lw1, lb1, lw2, lb2, lw3, lb3)
    LOADW(3, rw1, rb1, rw2, rb2, rw3, rb3)
    __syncthreads();

    const float* xp = x + (size_t)bc * XHW;
    float*       op = out + (size_t)bc * HW2;

    // ---- Phase 1a: top & bottom border MLPs (read x rows 0,1 / 222,223) ----
    if (t < HH) {
        const unsigned l = t;
        float s[2][3];
        // top (padded rows 1,2 = x rows 0,1; padded cols l..l+2 = x cols l-1..l+1)
#pragma unroll
        for (int r = 0; r < 2; ++r)
#pragma unroll
            for (int k = 0; k < 3; ++k) {
                unsigned xc = l + (unsigned)k - 1u;  // wraps huge if OOB
                s[r][k] = (xc < (unsigned)WW) ? xp[r * WW + xc] : 0.f;
            }
        float tres = mlp_eval(s, wts[0]);
        op[l + 1u] = tres;                               // padded row 0
        if (l < 2u)        Lcol[0][l] = tres;            // padded (0, 1+l)
        if (l >= HH - 2u)  Rcol[0][l - (HH - 2u)] = tres;// padded (0, 223+(l-222))
        // bottom (padded rows 223,224 = x rows 222,223)
#pragma unroll
        for (int r = 0; r < 2; ++r)
#pragma unroll
            for (int k = 0; k < 3; ++k) {
                unsigned xc = l + (unsigned)k - 1u;
                s[r][k] = (xc < (unsigned)WW) ? xp[(HH - 2u + r) * WW + xc] : 0.f;
            }
        float bres = mlp_eval(s, wts[1]);
        op[(H2 - 1u) * W2 + l + 1u] = bres;              // padded row 225
        if (l < 2u)        Lcol[H2 - 1][l] = bres;
        if (l >= HH - 2u)  Rcol[H2 - 1][l - (HH - 2u)] = bres;
    } else if (t == 255u) {
        // corners (nothing else ever writes them; output must be 0 there)
        op[0]                       = 0.f;
        op[W2 - 1]                  = 0.f;
        op[(H2 - 1u) * W2]          = 0.f;
        op[(H2 - 1u) * W2 + W2 - 1] = 0.f;
    }

    // ---- Phase 1b: interior copy (aligned f4 loads, dword-aligned f4 stores)
    for (unsigned f = t; f < F4PP; f += 256u) {
        const unsigned h = f / 56u;          // x row 0..223
        const unsigned j = f % 56u;          // float4 index within row
        const float4 v = *reinterpret_cast<const float4*>(xp + h * WW + 4u * j);
        *reinterpret_cast<float4*>(op + (h + 1u) * W2 + 1u + 4u * j) = v;
        if (j == 0u) {                        // x cols 0,1 -> padded cols 1,2
            Lcol[h + 1u][0] = v.x;
            Lcol[h + 1u][1] = v.y;
        } else if (j == 55u) {                // x cols 222,223 -> padded 223,224
            Rcol[h + 1u][0] = v.z;
            Rcol[h + 1u][1] = v.w;
        }
    }

    __syncthreads();

    // ---- Phase 2: left & right border MLPs, entirely from LDS ----
    for (unsigned idx = t; idx < 2u * HH; idx += 256u) {
        const unsigned side = idx / (unsigned)HH;  // 0=left 1=right
        const unsigned l    = idx % (unsigned)HH;
        float s[2][3];
        if (side == 0u) {
#pragma unroll
            for (int r = 0; r < 2; ++r)
#pragma unroll
                for (int k = 0; k < 3; ++k) s[r][k] = Lcol[l + (unsigned)k][r];
            op[(l + 1u) * W2] = mlp_eval(s, wts[2]);
        } else {
#pragma unroll
            for (int r = 0; r < 2; ++r)
#pragma unroll
                for (int k = 0; k < 3; ++k) s[r][k] = Rcol[l + (unsigned)k][r];
            op[(l + 1u) * W2 + (W2 - 1u)] = mlp_eval(s, wts[3]);
        }
    }
}

// ---------------------------------------------------------------------------
extern "C" void kernel_launch(void* const* d_in, const int* in_sizes, int n_in,
                              void* d_out, int out_size, void* d_ws,
                              size_t ws_size, hipStream_t stream) {
    const float* x = (const float*)d_in[0];
    const float* w[24];
    for (int i = 0; i < 24; ++i) w[i] = (const float*)d_in[1 + i];
    float* out = (float*)d_out;

    fused_pad_k<<<dim3(NPLANE), dim3(256), 0, stream>>>(
        x, out,
        w[0], w[1], w[2], w[3], w[4], w[5],       // top
        w[6], w[7], w[8], w[9], w[10], w[11],     // bottom
        w[12], w[13], w[14], w[15], w[16], w[17], // left
        w[18], w[19], w[20], w[21], w[22], w[23]);// right
}

// Round 3
// 222.393 us; speedup vs baseline: 1.6748x; 1.6748x over previous
//
#include <hip/hip_runtime.h>

// Problem constants (from reference)
#define BB   32
#define CC   64
#define HH   224
#define WW   224
#define H2   226
#define W2   226
#define HID  8

constexpr unsigned NPLANE = BB * CC;      // 2048 (b,c) planes
constexpr unsigned XHW    = HH * WW;      // 50176 floats per x plane
constexpr unsigned HW2    = H2 * W2;      // 51076 floats per out plane
constexpr unsigned NTOT   = NPLANE * HW2; // 104,603,648 out elements
constexpr unsigned NTOT4  = NTOT / 4;     // 26,150,912 (divisible by 256)
constexpr unsigned NBORD  = NPLANE * HH;  // 458,752 per border

// ---------------------------------------------------------------------------
// Kernel 1: padded copy. One float4 of `out` per thread (16B-aligned stores).
// Fast path (interior, same row): source x[s..s+3] is misaligned by r=s&3
// (always 1 or 3); reconstruct from two aligned float4 loads.
// Max fast-path B-read = plane's last element -> never OOB.
// ---------------------------------------------------------------------------
__global__ __launch_bounds__(256) void pad_copy_k(const float* __restrict__ x,
                                                  float* __restrict__ out) {
    const unsigned tid = blockIdx.x * 256u + threadIdx.x;
    const unsigned e   = tid * 4u;
    const unsigned bc  = e / HW2;
    const unsigned rem = e - bc * HW2;
    const unsigned h   = rem / W2;
    const unsigned w   = rem - h * W2;
    float4 v;
    if (h >= 1u && h <= (unsigned)HH && w >= 1u && w + 3u <= (unsigned)WW) {
        const unsigned s    = bc * XHW + (h - 1u) * WW + (w - 1u);
        const unsigned base = s & ~3u;
        const float4 A  = *reinterpret_cast<const float4*>(x + base);
        const float4 Bv = *reinterpret_cast<const float4*>(x + base + 4u);
        if ((s & 3u) == 1u) v = make_float4(A.y, A.z, A.w, Bv.x);
        else                v = make_float4(A.w, Bv.x, Bv.y, Bv.z);  // r==3
    } else {
        float vv[4];
        unsigned ww = w, hh = h, bcc = bc;
#pragma unroll
        for (int j = 0; j < 4; ++j) {
            unsigned hi = hh - 1u, wi = ww - 1u;  // wrap-huge if 0
            vv[j] = (hi < (unsigned)HH && wi < (unsigned)WW)
                        ? x[bcc * XHW + hi * (unsigned)WW + wi]
                        : 0.f;
            ++ww;
            if (ww == (unsigned)W2) { ww = 0; ++hh; if (hh == (unsigned)H2) { hh = 0; ++bcc; } }
        }
        v = make_float4(vv[0], vv[1], vv[2], vv[3]);
    }
    reinterpret_cast<float4*>(out)[tid] = v;
}

// ---------------------------------------------------------------------------
// MLP: s[2][3] -> scalar. Weights in LDS: [w1 48][b1 8][w2 64][b2 8][w3 8][b3]
// ---------------------------------------------------------------------------
__device__ __forceinline__ float mlp_eval(const float s[2][3],
                                          const float* __restrict__ W) {
    const float* W1  = W;
    const float* B1  = W + 48;
    const float* W2m = W + 56;
    const float* B2  = W + 120;
    const float* W3  = W + 128;
    const float  b3  = W[136];
    float y1[HID];
#pragma unroll
    for (int h = 0; h < HID; ++h) {
        float a = B1[h];
#pragma unroll
        for (int r = 0; r < 2; ++r)
#pragma unroll
            for (int k = 0; k < 3; ++k)
                a = fmaf(s[r][k], W1[h * 6 + r * 3 + k], a);
        y1[h] = fmaxf(a, 0.f);
    }
    float y2[HID];
#pragma unroll
    for (int o = 0; o < HID; ++o) {
        float a = B2[o];
#pragma unroll
        for (int h = 0; h < HID; ++h) a = fmaf(y1[h], W2m[o * 8 + h], a);
        y2[o] = fmaxf(a, 0.f);
    }
    float a = b3;
#pragma unroll
    for (int h = 0; h < HID; ++h) a = fmaf(y2[h], W3[h], a);
    return fmaxf(a, 0.f);
}

__device__ __forceinline__ void load_wts(unsigned t, float* W,
                                         const float* w1, const float* b1,
                                         const float* w2, const float* b2,
                                         const float* w3, const float* b3) {
    if (t < 48u) W[t] = w1[t];
    if (t < 64u) W[56u + t] = w2[t];
    if (t < 8u) {
        W[48u + t]  = b1[t];
        W[120u + t] = b2[t];
        W[128u + t] = w3[t];
    }
    if (t == 0u) W[136] = b3[0];
}

// ---------------------------------------------------------------------------
// Kernel 2: top (blockIdx.y==0) / bottom (==1) borders. Reads x rows
// {0,1}/{222,223}; writes out rows 0/225, cols 1..224.
// ---------------------------------------------------------------------------
__global__ __launch_bounds__(256) void border_tb_k(
    const float* __restrict__ x, float* __restrict__ out,
    const float* tw1, const float* tb1, const float* tw2, const float* tb2,
    const float* tw3, const float* tb3,
    const float* bw1, const float* bb1, const float* bw2, const float* bb2,
    const float* bw3, const float* bb3) {
    const bool top = (blockIdx.y == 0);
    __shared__ float W[137];
    load_wts(threadIdx.x,
             W,
             top ? tw1 : bw1, top ? tb1 : bb1, top ? tw2 : bw2,
             top ? tb2 : bb2, top ? tw3 : bw3, top ? tb3 : bb3);
    __syncthreads();

    const unsigned gid = blockIdx.x * 256u + threadIdx.x;
    const unsigned l   = gid % (unsigned)HH;
    const unsigned bc  = gid / (unsigned)HH;

    const unsigned r0 = top ? 0u : (unsigned)(HH - 2);
    float s[2][3];
#pragma unroll
    for (int r = 0; r < 2; ++r)
#pragma unroll
        for (int k = 0; k < 3; ++k) {
            unsigned xc = l + (unsigned)k - 1u;  // wrap-huge if OOB
            s[r][k] = (xc < (unsigned)WW)
                          ? x[bc * XHW + (r0 + (unsigned)r) * (unsigned)WW + xc]
                          : 0.f;
        }
    const float res = mlp_eval(s, W);
    const unsigned orow = top ? 0u : (unsigned)(H2 - 1);
    out[bc * HW2 + orow * (unsigned)W2 + (l + 1u)] = res;
}

// ---------------------------------------------------------------------------
// Kernel 3: left (blockIdx.y==0) / right (==1) borders. Interior rows read
// straight from x (aligned float2: cols {0,1} or {222,223}); padded rows
// 0/225 read the tb results from out (8 scalars/plane). Writes cols 0/225.
// ---------------------------------------------------------------------------
__global__ __launch_bounds__(256) void border_lr_k(
    const float* __restrict__ x, float* __restrict__ out,
    const float* lw1, const float* lb1, const float* lw2, const float* lb2,
    const float* lw3, const float* lb3,
    const float* rw1, const float* rb1, const float* rw2, const float* rb2,
    const float* rw3, const float* rb3) {
    const bool left = (blockIdx.y == 0);
    __shared__ float W[137];
    load_wts(threadIdx.x,
             W,
             left ? lw1 : rw1, left ? lb1 : rb1, left ? lw2 : rw2,
             left ? lb2 : rb2, left ? lw3 : rw3, left ? lb3 : rb3);
    __syncthreads();

    const unsigned gid = blockIdx.x * 256u + threadIdx.x;
    const unsigned l   = gid % (unsigned)HH;  // writes padded row l+1
    const unsigned bc  = gid / (unsigned)HH;

    const unsigned cc0 = left ? 0u : (unsigned)(WW - 2);  // x col base
    const unsigned oc0 = left ? 1u : (unsigned)(W2 - 3);  // out col base (rows 0/225)
    float s[2][3];
#pragma unroll
    for (int k = 0; k < 3; ++k) {
        const unsigned pr = l + (unsigned)k;  // padded row l..l+2
        float v0, v1;
        if (pr == 0u) {
            v0 = out[bc * HW2 + oc0];
            v1 = out[bc * HW2 + oc0 + 1u];
        } else if (pr == (unsigned)(H2 - 1)) {
            v0 = out[bc * HW2 + (unsigned)(H2 - 1) * W2 + oc0];
            v1 = out[bc * HW2 + (unsigned)(H2 - 1) * W2 + oc0 + 1u];
        } else {
            const float2 t2 = *reinterpret_cast<const float2*>(
                x + bc * XHW + (pr - 1u) * (unsigned)WW + cc0);
            v0 = t2.x;
            v1 = t2.y;
        }
        s[0][k] = v0;
        s[1][k] = v1;
    }
    const float res = mlp_eval(s, W);
    out[bc * HW2 + (l + 1u) * (unsigned)W2 + (left ? 0u : (unsigned)(W2 - 1))] = res;
}

// ---------------------------------------------------------------------------
extern "C" void kernel_launch(void* const* d_in, const int* in_sizes, int n_in,
                              void* d_out, int out_size, void* d_ws,
                              size_t ws_size, hipStream_t stream) {
    const float* x = (const float*)d_in[0];
    const float* w[24];
    for (int i = 0; i < 24; ++i) w[i] = (const float*)d_in[1 + i];
    float* out = (float*)d_out;

    // 1) padded copy (dominant traffic; writes zeros in ring, overwritten below)
    pad_copy_k<<<dim3(NTOT4 / 256u), dim3(256), 0, stream>>>(x, out);

    // 2) top + bottom borders (read x only; write rows 0/225)
    border_tb_k<<<dim3(NBORD / 256u, 2), dim3(256), 0, stream>>>(
        x, out, w[0], w[1], w[2], w[3], w[4], w[5],
        w[6], w[7], w[8], w[9], w[10], w[11]);

    // 3) left + right borders (read x cols + tb results; write cols 0/225)
    border_lr_k<<<dim3(NBORD / 256u, 2), dim3(256), 0, stream>>>(
        x, out, w[12], w[13], w[14], w[15], w[16], w[17],
        w[18], w[19], w[20], w[21], w[22], w[23]);
}